// Round 6
// baseline (317.724 us; speedup 1.0000x reference)
//
#include <hip/hip_runtime.h>

typedef short short8 __attribute__((ext_vector_type(8)));
typedef short short4v __attribute__((ext_vector_type(4)));
typedef float f4 __attribute__((ext_vector_type(4)));

#define NB 4
#define NHW 128
#define NPX (NHW*NHW)
#define NWIN 31
#define NL (NWIN*NWIN)
// 64-wide row, 8-col-block XOR swizzle (conflict-free b128 row reads)
#define SWV(r,c) (((r)<<6) + (((((c)>>3) ^ ((r)&7))<<3) | ((c)&7)))
#define MFMA(a,b,c) __builtin_amdgcn_mfma_f32_16x16x32_bf16(a,b,c,0,0,0)

__device__ __forceinline__ short f2bf(float f) {
    unsigned u = __float_as_uint(f);
    u += 0x7fffu + ((u >> 16) & 1u);   // RNE; inputs never NaN/inf
    return (short)(u >> 16);
}
__device__ __forceinline__ float bf2f(short v) {
    return __uint_as_float(((unsigned)(unsigned short)v) << 16);
}

// ---------------- SE: global average pool per (b,c) ----------------
__global__ void k_pool(const float* __restrict__ high, float* __restrict__ pooled) {
    int bc = blockIdx.x;
    const float* src = high + (size_t)bc * NPX;
    float s = 0.f;
    for (int i = threadIdx.x; i < NPX; i += 256) s += src[i];
    for (int off = 32; off > 0; off >>= 1) s += __shfl_down(s, off);
    __shared__ float red[4];
    int lane = threadIdx.x & 63, wv = threadIdx.x >> 6;
    if (lane == 0) red[wv] = s;
    __syncthreads();
    if (threadIdx.x == 0)
        pooled[bc] = (red[0] + red[1] + red[2] + red[3]) * (1.f / NPX);
}

// ---------------- SE: gate s[b,c] ----------------
__global__ void k_gate(const float* __restrict__ pooled,
                       const float* __restrict__ w10, const float* __restrict__ w20,
                       const float* __restrict__ w11, const float* __restrict__ w21,
                       const float* __restrict__ w12, const float* __restrict__ w22,
                       float* __restrict__ sgate) {
    __shared__ float pl[256];
    int t = threadIdx.x;
    pl[t] = pooled[t];
    __syncthreads();
    int b = t >> 6, c = t & 63;
    const float* w1; const float* w2; int o0, gc;
    if (c < 22)      { w1 = w10; w2 = w20; o0 = 0;  gc = 22; }
    else if (c < 43) { w1 = w11; w2 = w21; o0 = 22; gc = 21; }
    else             { w1 = w12; w2 = w22; o0 = 43; gc = 21; }
    float a = 0.f;
    for (int k = 0; k < gc; ++k) a += pl[b*64 + o0 + k] * w1[k];
    a = fmaxf(a, 0.f);
    float z = a * w2[c - o0];
    sgate[t] = 1.f / (1.f + __expf(-z));
}

// windows covering coordinate x (ws=8, stride 4): [lo,hi]
__device__ __forceinline__ void wrange(int x, int& lo, int& hi) {
    lo = (x >= 7) ? ((x - 4) >> 2) : 0;
    hi = x >> 2; if (hi > 30) hi = 30;
}

// ---------------- per-pixel projections (GEMM), fused fp32->bf16 ----------------
// One block per (b, image row). bf16 transposed LDS tile [px][c] swizzled;
// all MFMA fragment reads are ds_read_b128.
// EMIT bit0: Q -> ch-last [b][px][64]; bit1: K -> ch-last; bit2: V -> planar [b][64][px]
template<int EMIT>
__global__ __launch_bounds__(256, 6) void k_proj(
    const float* __restrict__ src, const float* __restrict__ gate,
    const float* __restrict__ Wq, const float* __restrict__ Wk, const float* __restrict__ Wv,
    short* __restrict__ Qp, short* __restrict__ Kp, short* __restrict__ Vp) {
    __shared__ __align__(16) short T[8192];     // X row tile, [px][c] swizzled bf16
    int b = blockIdx.x >> 7, row = blockIdx.x & 127;
    int t = threadIdx.x;
    const float* sp = src + (size_t)b*64*NPX + row*NHW;
    // lane = channel, waves interleave px by 4 -> full-line L1 reuse;
    // LDS writes: lanes span c at fixed px -> conflict-free transpose store
    #pragma unroll
    for (int i = 0; i < 8; ++i) {
        int f = t + i*256;
        int c = f & 63, px = (f >> 6) << 2;
        float4 v = *(const float4*)(sp + (size_t)c*NPX + px);
        float g = gate ? gate[b*64 + c] : 1.f;
        T[SWV(px + 0, c)] = f2bf(v.x * g);
        T[SWV(px + 1, c)] = f2bf(v.y * g);
        T[SWV(px + 2, c)] = f2bf(v.z * g);
        T[SWV(px + 3, c)] = f2bf(v.w * g);
    }
    __syncthreads();
    int w = t >> 6, ln = t & 63, l16 = ln & 15, quad = ln >> 4;
    int orow = 16*w + l16;
    short8 wq[2], wk[2], wv[2];
    #pragma unroll
    for (int kf = 0; kf < 2; ++kf) {
        if (EMIT & 1) {
            const float* p = Wq + orow*64 + kf*32 + quad*8;
            #pragma unroll
            for (int j = 0; j < 8; ++j) wq[kf][j] = f2bf(p[j]);
        }
        if (EMIT & 2) {
            const float* p = Wk + orow*64 + kf*32 + quad*8;
            #pragma unroll
            for (int j = 0; j < 8; ++j) wk[kf][j] = f2bf(p[j]);
        }
        if (EMIT & 4) {
            const float* p = Wv + orow*64 + kf*32 + quad*8;
            #pragma unroll
            for (int j = 0; j < 8; ++j) wv[kf][j] = f2bf(p[j]);
        }
    }
    #pragma unroll
    for (int nt = 0; nt < 8; ++nt) {
        int px = nt*16 + l16;
        short8 xb0 = *(const short8*)(T + SWV(px, quad*8));
        short8 xb1 = *(const short8*)(T + SWV(px, 32 + quad*8));
        size_t clbase = ((size_t)b*NPX + row*NHW + px)*64 + 16*w + quad*4;
        if (EMIT & 1) {
            f4 acc = {0.f,0.f,0.f,0.f};
            acc = MFMA(wq[0], xb0, acc); acc = MFMA(wq[1], xb1, acc);
            short4v sv;
            #pragma unroll
            for (int r = 0; r < 4; ++r) sv[r] = f2bf(acc[r]);
            *(short4v*)(Qp + clbase) = sv;
        }
        if (EMIT & 2) {
            f4 acc = {0.f,0.f,0.f,0.f};
            acc = MFMA(wk[0], xb0, acc); acc = MFMA(wk[1], xb1, acc);
            short4v sv;
            #pragma unroll
            for (int r = 0; r < 4; ++r) sv[r] = f2bf(acc[r]);
            *(short4v*)(Kp + clbase) = sv;
        }
        if (EMIT & 4) {
            f4 acc = {0.f,0.f,0.f,0.f};
            acc = MFMA(wv[0], xb0, acc); acc = MFMA(wv[1], xb1, acc);
            #pragma unroll
            for (int r = 0; r < 4; ++r)
                Vp[((size_t)(b*64 + 16*w + quad*4 + r))*NPX + row*NHW + px] = f2bf(acc[r]);
        }
    }
}

// ---------------- windowed cross attention (S, softmax, PV only) ----------------
// Handles npass passes via grid: pass = blockIdx.x / (nb*NL).
// scr: [pass][4 parity][nb][px][64] bf16; same-parity windows tile the plane.
__global__ __launch_bounds__(256, 8) void k_attn(
    const short* __restrict__ Q0, const short* __restrict__ K0, const short* __restrict__ V0,
    const short* __restrict__ Q1, const short* __restrict__ K1, const short* __restrict__ V1,
    short* __restrict__ scr, size_t scr_stride, int nb) {
    __shared__ __align__(16) short Pb[4][1024];   // per-wave P [16 n][64 m], swizzled
    int bidx = blockIdx.x;
    int per = nb * NL;
    int pass = bidx / per; int rem2 = bidx - pass*per;
    int b = rem2 / NL, l = rem2 - b*NL;
    const short* Qp = pass ? Q1 : Q0;
    const short* Kp = pass ? K1 : K0;
    const short* Vp = pass ? V1 : V0;
    short* scrp = scr + (size_t)pass * scr_stride;
    int wr = l / NWIN, wc = l - (l/NWIN)*NWIN;
    int row0 = wr*4, col0 = wc*4;
    int parity = (wr & 1)*2 + (wc & 1);
    int t = threadIdx.x, w = t >> 6, ln = t & 63, l16 = ln & 15, quad = ln >> 4;
    int h = w;
    short* PT = Pb[w];
    short8 z = {0,0,0,0,0,0,0,0};

    // K B-frags: B[k=d][col=m], m = mt*16+l16, d = quad*8+j (quad<2)
    short8 kb[4];
    #pragma unroll
    for (int mt = 0; mt < 4; ++mt) {
        int m = mt*16 + l16;
        int px = (row0 + (m >> 3))*NHW + col0 + (m & 7);
        kb[mt] = (quad < 2) ? *(const short8*)(Kp + ((size_t)b*NPX + px)*64 + h*16 + quad*8) : z;
    }
    // V A-frags: A[row=d=l16][k=m]; planar V: row rr, 8 consecutive cols
    short8 va0, va1;
    {
        const short* vb = Vp + ((size_t)(b*64 + h*16 + l16))*NPX;
        const short* p0 = vb + (row0 + quad)*NHW + col0;
        const short* p1 = vb + (row0 + 4 + quad)*NHW + col0;
        short4v a = *(const short4v*)p0, bq = *(const short4v*)(p0 + 4);
        short4v c = *(const short4v*)p1, d = *(const short4v*)(p1 + 4);
        #pragma unroll
        for (int j = 0; j < 4; ++j) { va0[j] = a[j]; va0[4+j] = bq[j]; va1[j] = c[j]; va1[4+j] = d[j]; }
    }

    #pragma unroll
    for (int ntl = 0; ntl < 4; ++ntl) {
        int n = ntl*16 + l16;
        int px = (row0 + (n >> 3))*NHW + col0 + (n & 7);
        short8 qa = (quad < 2) ? *(const short8*)(Qp + ((size_t)b*NPX + px)*64 + h*16 + quad*8) : z;
        f4 s[4];
        #pragma unroll
        for (int mt = 0; mt < 4; ++mt) {
            f4 acc = {0.f,0.f,0.f,0.f};
            s[mt] = MFMA(qa, kb[mt], acc);
        }
        // softmax over m (4 regs x 16 lanes); no max pass (|S|*0.25 << 30), clamp for safety
        f4 sum = {0.f,0.f,0.f,0.f};
        #pragma unroll
        for (int mt = 0; mt < 4; ++mt)
            #pragma unroll
            for (int r = 0; r < 4; ++r) {
                float e = __expf(fminf(s[mt][r]*0.25f, 30.f));
                s[mt][r] = e; sum[r] += e;
            }
        #pragma unroll
        for (int d = 1; d < 16; d <<= 1)
            #pragma unroll
            for (int r = 0; r < 4; ++r) sum[r] += __shfl_xor(sum[r], d);
        #pragma unroll
        for (int r = 0; r < 4; ++r) sum[r] = 1.f / sum[r];
        #pragma unroll
        for (int mt = 0; mt < 4; ++mt)
            #pragma unroll
            for (int r = 0; r < 4; ++r)
                PT[SWV(quad*4 + r, mt*16 + l16)] = f2bf(s[mt][r] * sum[r]);
        // O[d][n] = V_h P^T  (in-wave LDS RAW, waitcnt-ordered; no barrier needed)
        f4 o = {0.f,0.f,0.f,0.f};
        o = MFMA(va0, *(const short8*)(PT + SWV(l16, quad*8)), o);
        o = MFMA(va1, *(const short8*)(PT + SWV(l16, 32 + quad*8)), o);
        short4v sv;
        #pragma unroll
        for (int r = 0; r < 4; ++r) sv[r] = f2bf(o[r]);
        *(short4v*)(scrp + (((size_t)(parity*nb + b))*NPX + px)*64 + h*16 + quad*4) = sv;
    }
}

// ---------------- fold from parity planes + mask + 1x1 proj + residual ----------------
__global__ __launch_bounds__(256, 6) void k_gather(
    const short* __restrict__ scr, size_t scr_stride,
    const float* __restrict__ r0, const float* __restrict__ r1,
    const float* __restrict__ wp0, const float* __restrict__ wp1,
    float* __restrict__ o0, float* __restrict__ o1, int nb) {
    __shared__ __align__(16) short G[8192];       // [px 0..127][64 ch], swizzled
    int bidx = blockIdx.x;
    int per = nb * NHW;
    int pass = bidx / per; int rem2 = bidx - pass*per;
    int b = rem2 >> 7, hh = rem2 & 127;
    const short* scrp = scr + (size_t)pass * scr_stride;
    const float* resid = pass ? r1 : r0;
    const float* wproj = pass ? wp1 : wp0;
    float* outp = pass ? o1 : o0;
    int t = threadIdx.x;
    int p = t >> 1, c0 = (t & 1)*32;
    int rlo, rhi, clo, chi;
    wrange(hh, rlo, rhi); wrange(p, clo, chi);
    float vr[2], vc[2];
    vr[0] = (rhi > rlo || (rlo & 1) == 0) ? 1.f : 0.f;
    vr[1] = (rhi > rlo || (rlo & 1) == 1) ? 1.f : 0.f;
    vc[0] = (chi > clo || (clo & 1) == 0) ? 1.f : 0.f;
    vc[1] = (chi > clo || (clo & 1) == 1) ? 1.f : 0.f;
    float g[32];
    #pragma unroll
    for (int k = 0; k < 32; ++k) g[k] = 0.f;
    #pragma unroll
    for (int par = 0; par < 4; ++par) {
        float wgt = vr[par >> 1] * vc[par & 1];
        const short* srcp = scrp + (((size_t)(par*nb + b))*NPX + hh*NHW + p)*64 + c0;
        #pragma unroll
        for (int k4 = 0; k4 < 4; ++k4) {
            short8 v = *(const short8*)(srcp + k4*8);
            #pragma unroll
            for (int j = 0; j < 8; ++j) g[k4*8 + j] += wgt * bf2f(v[j]);
        }
    }
    float inv = 1.f / ((float)(rhi - rlo + 1) * (float)(chi - clo + 1));
    #pragma unroll
    for (int k4 = 0; k4 < 4; ++k4) {
        short8 v;
        #pragma unroll
        for (int j = 0; j < 8; ++j) v[j] = f2bf(g[k4*8 + j] * inv);
        *(short8*)(G + SWV(p, c0 + k4*8)) = v;
    }
    __syncthreads();
    int w = t >> 6, ln = t & 63, l16 = ln & 15, quad = ln >> 4;
    short8 wa0, wa1;
    {
        const float* p0 = wproj + (16*w + l16)*64 + quad*8;
        #pragma unroll
        for (int j = 0; j < 8; ++j) { wa0[j] = f2bf(p0[j]); wa1[j] = f2bf(p0[32 + j]); }
    }
    #pragma unroll
    for (int pt = 0; pt < 8; ++pt) {
        f4 acc = {0.f,0.f,0.f,0.f};
        acc = MFMA(wa0, *(const short8*)(G + SWV(pt*16 + l16, quad*8)), acc);
        acc = MFMA(wa1, *(const short8*)(G + SWV(pt*16 + l16, 32 + quad*8)), acc);
        #pragma unroll
        for (int r = 0; r < 4; ++r) {
            size_t gi = (((size_t)(b*64 + 16*w + quad*4 + r))*NHW + hh)*NHW + pt*16 + l16;
            outp[gi] = resid[gi] + acc[r];
        }
    }
}

extern "C" void kernel_launch(void* const* d_in, const int* in_sizes, int n_in,
                              void* d_out, int out_size, void* d_ws, size_t ws_size,
                              hipStream_t stream) {
    const float* low  = (const float*)d_in[0];
    const float* high = (const float*)d_in[1];
    const float* w_ql = (const float*)d_in[2];
    const float* w_kh = (const float*)d_in[3];
    const float* w_vh = (const float*)d_in[4];
    const float* w_qh = (const float*)d_in[5];
    const float* w_kl = (const float*)d_in[6];
    const float* w_vl = (const float*)d_in[7];
    const float* w_pl = (const float*)d_in[8];
    const float* w_ph = (const float*)d_in[9];
    float* out = (float*)d_out;
    float* pooled = (float*)d_ws;
    float* sgate  = pooled + 256;
    short* base = (short*)((char*)d_ws + 2048);
    const size_t PL = (size_t)NB * NPX * 64;            // elems per bf16 plane (8.39 MB)
    const size_t plane_f = (size_t)NB * 64 * NPX;       // fp32 out plane elems
    const size_t SCR = 4 * PL;                          // scr elems per pass (33.5 MB)
    size_t need_fused  = 2048 + (6*PL + 2*SCR) * sizeof(short);
    size_t need_serial = 2048 + (6*PL + SCR) * sizeof(short);
    size_t scr_elems_per_b = 4 * (size_t)NPX * 64;

    k_pool<<<dim3(NB*64), dim3(256), 0, stream>>>(high, pooled);
    k_gate<<<dim3(1), dim3(256), 0, stream>>>(pooled,
        (const float*)d_in[10], (const float*)d_in[11],
        (const float*)d_in[12], (const float*)d_in[13],
        (const float*)d_in[14], (const float*)d_in[15], sgate);

    if (ws_size >= need_serial) {
        short* QL = base;        short* KL = base + PL;   short* VL = base + 2*PL;
        short* QH = base + 3*PL; short* KH = base + 4*PL; short* VH = base + 5*PL;
        short* scr = base + 6*PL;
        k_proj<7><<<dim3(NB*NHW), dim3(256), 0, stream>>>(low,  nullptr, w_ql, w_kl, w_vl, QL, KL, VL);
        k_proj<7><<<dim3(NB*NHW), dim3(256), 0, stream>>>(high, sgate,   w_qh, w_kh, w_vh, QH, KH, VH);
        if (ws_size >= need_fused) {
            // both passes in one attn dispatch, both folds in one gather dispatch
            k_attn<<<dim3(2*NB*NL), dim3(256), 0, stream>>>(QL, KH, VH, QH, KL, VL, scr, SCR, NB);
            k_gather<<<dim3(2*NB*NHW), dim3(256), 0, stream>>>(scr, SCR, low, high,
                w_pl, w_ph, out, out + plane_f, NB);
        } else {
            k_attn<<<dim3(NB*NL), dim3(256), 0, stream>>>(QL, KH, VH, nullptr, nullptr, nullptr, scr, 0, NB);
            k_gather<<<dim3(NB*NHW), dim3(256), 0, stream>>>(scr, 0, low, nullptr,
                w_pl, nullptr, out, nullptr, NB);
            k_attn<<<dim3(NB*NL), dim3(256), 0, stream>>>(QH, KL, VL, nullptr, nullptr, nullptr, scr, 0, NB);
            k_gather<<<dim3(NB*NHW), dim3(256), 0, stream>>>(scr, 0, high, nullptr,
                w_ph, nullptr, out + plane_f, nullptr, NB);
        }
    } else {
        // trio mode: 3 plane slots + batch-chunked scr
        short* P0 = base; short* P1 = base + PL; short* P2 = base + 2*PL;
        short* scr = base + 3*PL;
        int nbc = 0;
        for (int n = NB; n >= 1; n >>= 1)
            if (ws_size >= 2048 + (3*PL + n*scr_elems_per_b)*sizeof(short)) { nbc = n; break; }
        if (nbc == 0) nbc = 1;
        for (int pass = 0; pass < 2; ++pass) {
            const float* qsrc = pass ? high : low;
            const float* ksrc = pass ? low  : high;
            const float* qg   = pass ? sgate : nullptr;
            const float* kg   = pass ? nullptr : sgate;
            const float* Wq   = pass ? w_qh : w_ql;
            const float* Wk   = pass ? w_kl : w_kh;
            const float* Wv   = pass ? w_vl : w_vh;
            const float* Wp   = pass ? w_ph : w_pl;
            const float* resid = pass ? high : low;
            float* op = out + (size_t)pass * plane_f;
            k_proj<1><<<dim3(NB*NHW), dim3(256), 0, stream>>>(qsrc, qg, Wq, nullptr, nullptr, P0, nullptr, nullptr);
            k_proj<6><<<dim3(NB*NHW), dim3(256), 0, stream>>>(ksrc, kg, nullptr, Wk, Wv, nullptr, P1, P2);
            for (int b0 = 0; b0 < NB; b0 += nbc) {
                int nb = (NB - b0) < nbc ? (NB - b0) : nbc;
                size_t boff = (size_t)b0 * NPX * 64;
                k_attn<<<dim3(nb*NL), dim3(256), 0, stream>>>(P0 + boff, P1 + boff, P2 + boff,
                    nullptr, nullptr, nullptr, scr, 0, nb);
                k_gather<<<dim3(nb*NHW), dim3(256), 0, stream>>>(scr, 0, resid + boff, nullptr,
                    Wp, nullptr, op + boff, nullptr, nb);
            }
        }
    }
}

// Round 7
// 246.639 us; speedup vs baseline: 1.2882x; 1.2882x over previous
//
#include <hip/hip_runtime.h>

typedef short short8 __attribute__((ext_vector_type(8)));
typedef short short4v __attribute__((ext_vector_type(4)));
typedef float f4 __attribute__((ext_vector_type(4)));

#define NB 4
#define NHW 128
#define NPX (NHW*NHW)
#define NWIN 31
#define NL (NWIN*NWIN)
// 64-wide row, 8-col-block XOR swizzle (conflict-free b128 row reads)
#define SWV(r,c) (((r)<<6) + (((((c)>>3) ^ ((r)&7))<<3) | ((c)&7)))
#define MFMA(a,b,c) __builtin_amdgcn_mfma_f32_16x16x32_bf16(a,b,c,0,0,0)

__device__ __forceinline__ short f2bf(float f) {
    unsigned u = __float_as_uint(f);
    u += 0x7fffu + ((u >> 16) & 1u);   // RNE; inputs never NaN/inf
    return (short)(u >> 16);
}
__device__ __forceinline__ float bf2f(short v) {
    return __uint_as_float(((unsigned)(unsigned short)v) << 16);
}

// ---------------- SE: global average pool per (b,c) ----------------
__global__ void k_pool(const float* __restrict__ high, float* __restrict__ pooled) {
    int bc = blockIdx.x;
    const float* src = high + (size_t)bc * NPX;
    float s = 0.f;
    for (int i = threadIdx.x; i < NPX; i += 256) s += src[i];
    for (int off = 32; off > 0; off >>= 1) s += __shfl_down(s, off);
    __shared__ float red[4];
    int lane = threadIdx.x & 63, wv = threadIdx.x >> 6;
    if (lane == 0) red[wv] = s;
    __syncthreads();
    if (threadIdx.x == 0)
        pooled[bc] = (red[0] + red[1] + red[2] + red[3]) * (1.f / NPX);
}

// ---------------- SE: gate s[b,c] ----------------
__global__ void k_gate(const float* __restrict__ pooled,
                       const float* __restrict__ w10, const float* __restrict__ w20,
                       const float* __restrict__ w11, const float* __restrict__ w21,
                       const float* __restrict__ w12, const float* __restrict__ w22,
                       float* __restrict__ sgate) {
    __shared__ float pl[256];
    int t = threadIdx.x;
    pl[t] = pooled[t];
    __syncthreads();
    int b = t >> 6, c = t & 63;
    const float* w1; const float* w2; int o0, gc;
    if (c < 22)      { w1 = w10; w2 = w20; o0 = 0;  gc = 22; }
    else if (c < 43) { w1 = w11; w2 = w21; o0 = 22; gc = 21; }
    else             { w1 = w12; w2 = w22; o0 = 43; gc = 21; }
    float a = 0.f;
    for (int k = 0; k < gc; ++k) a += pl[b*64 + o0 + k] * w1[k];
    a = fmaxf(a, 0.f);
    float z = a * w2[c - o0];
    sgate[t] = 1.f / (1.f + __expf(-z));
}

// windows covering coordinate x (ws=8, stride 4): [lo,hi]
__device__ __forceinline__ void wrange(int x, int& lo, int& hi) {
    lo = (x >= 7) ? ((x - 4) >> 2) : 0;
    hi = x >> 2; if (hi > 30) hi = 30;
}

// ---------------- per-pixel projections (GEMM), fused fp32->bf16 ----------------
// One block per (b, image row). bf16 transposed LDS tile [px][c] swizzled;
// all MFMA fragment reads are ds_read_b128.
// EMIT bit0: Q -> ch-last [b][px][64]; bit1: K -> ch-last; bit2: V -> planar [b][64][px]
template<int EMIT>
__global__ __launch_bounds__(256, 6) void k_proj(
    const float* __restrict__ src, const float* __restrict__ gate,
    const float* __restrict__ Wq, const float* __restrict__ Wk, const float* __restrict__ Wv,
    short* __restrict__ Qp, short* __restrict__ Kp, short* __restrict__ Vp) {
    __shared__ __align__(16) short T[8192];     // X row tile, [px][c] swizzled bf16
    int b = blockIdx.x >> 7, row = blockIdx.x & 127;
    int t = threadIdx.x;
    const float* sp = src + (size_t)b*64*NPX + row*NHW;
    // lane = channel, waves interleave px by 4 -> full-line L1 reuse;
    // LDS writes: lanes span c at fixed px -> conflict-free transpose store
    #pragma unroll
    for (int i = 0; i < 8; ++i) {
        int f = t + i*256;
        int c = f & 63, px = (f >> 6) << 2;
        float4 v = *(const float4*)(sp + (size_t)c*NPX + px);
        float g = gate ? gate[b*64 + c] : 1.f;
        T[SWV(px + 0, c)] = f2bf(v.x * g);
        T[SWV(px + 1, c)] = f2bf(v.y * g);
        T[SWV(px + 2, c)] = f2bf(v.z * g);
        T[SWV(px + 3, c)] = f2bf(v.w * g);
    }
    __syncthreads();
    int w = t >> 6, ln = t & 63, l16 = ln & 15, quad = ln >> 4;
    int orow = 16*w + l16;
    short8 wq[2], wk[2], wv[2];
    #pragma unroll
    for (int kf = 0; kf < 2; ++kf) {
        if (EMIT & 1) {
            const float* p = Wq + orow*64 + kf*32 + quad*8;
            #pragma unroll
            for (int j = 0; j < 8; ++j) wq[kf][j] = f2bf(p[j]);
        }
        if (EMIT & 2) {
            const float* p = Wk + orow*64 + kf*32 + quad*8;
            #pragma unroll
            for (int j = 0; j < 8; ++j) wk[kf][j] = f2bf(p[j]);
        }
        if (EMIT & 4) {
            const float* p = Wv + orow*64 + kf*32 + quad*8;
            #pragma unroll
            for (int j = 0; j < 8; ++j) wv[kf][j] = f2bf(p[j]);
        }
    }
    #pragma unroll
    for (int nt = 0; nt < 8; ++nt) {
        int px = nt*16 + l16;
        short8 xb0 = *(const short8*)(T + SWV(px, quad*8));
        short8 xb1 = *(const short8*)(T + SWV(px, 32 + quad*8));
        size_t clbase = ((size_t)b*NPX + row*NHW + px)*64 + 16*w + quad*4;
        if (EMIT & 1) {
            f4 acc = {0.f,0.f,0.f,0.f};
            acc = MFMA(wq[0], xb0, acc); acc = MFMA(wq[1], xb1, acc);
            short4v sv;
            #pragma unroll
            for (int r = 0; r < 4; ++r) sv[r] = f2bf(acc[r]);
            *(short4v*)(Qp + clbase) = sv;
        }
        if (EMIT & 2) {
            f4 acc = {0.f,0.f,0.f,0.f};
            acc = MFMA(wk[0], xb0, acc); acc = MFMA(wk[1], xb1, acc);
            short4v sv;
            #pragma unroll
            for (int r = 0; r < 4; ++r) sv[r] = f2bf(acc[r]);
            *(short4v*)(Kp + clbase) = sv;
        }
        if (EMIT & 4) {
            f4 acc = {0.f,0.f,0.f,0.f};
            acc = MFMA(wv[0], xb0, acc); acc = MFMA(wv[1], xb1, acc);
            #pragma unroll
            for (int r = 0; r < 4; ++r)
                Vp[((size_t)(b*64 + 16*w + quad*4 + r))*NPX + row*NHW + px] = f2bf(acc[r]);
        }
    }
}

// ---------------- windowed cross attention (S, softmax, PV only) ----------------
// SWZ=1 (fused, grid=8*NL): blockIdx%8 -> (pass,b) so each XCD owns one
// (pass,batch) plane (round-robin XCD dispatch) -> zero cross-XCD Q/K/V sharing.
// SWZ=0: linear indexing (serial/trio fallbacks).
// scr: [pass][4 parity][nb][px][64] bf16; same-parity windows tile the plane.
template<int SWZ>
__global__ __launch_bounds__(256, 6) void k_attn(
    const short* __restrict__ Q0, const short* __restrict__ K0, const short* __restrict__ V0,
    const short* __restrict__ Q1, const short* __restrict__ K1, const short* __restrict__ V1,
    short* __restrict__ scr, size_t scr_stride, int nb) {
    __shared__ __align__(16) short Pb[4][1024];   // per-wave P [16 n][64 m], swizzled
    int bidx = blockIdx.x;
    int pass, b, l;
    if (SWZ) {
        int region = bidx & 7;
        pass = region >> 2; b = region & 3; l = bidx >> 3;
    } else {
        int per = nb * NL;
        pass = bidx / per; int rem2 = bidx - pass*per;
        b = rem2 / NL; l = rem2 - b*NL;
    }
    const short* Qp = pass ? Q1 : Q0;
    const short* Kp = pass ? K1 : K0;
    const short* Vp = pass ? V1 : V0;
    short* scrp = scr + (size_t)pass * scr_stride;
    int wr = l / NWIN, wc = l - (l/NWIN)*NWIN;
    int row0 = wr*4, col0 = wc*4;
    int parity = (wr & 1)*2 + (wc & 1);
    int t = threadIdx.x, w = t >> 6, ln = t & 63, l16 = ln & 15, quad = ln >> 4;
    int h = w;
    short* PT = Pb[w];
    short8 z = {0,0,0,0,0,0,0,0};

    // K B-frags: B[k=d][col=m], m = mt*16+l16, d = quad*8+j (quad<2)
    short8 kb[4];
    #pragma unroll
    for (int mt = 0; mt < 4; ++mt) {
        int m = mt*16 + l16;
        int px = (row0 + (m >> 3))*NHW + col0 + (m & 7);
        kb[mt] = (quad < 2) ? *(const short8*)(Kp + ((size_t)b*NPX + px)*64 + h*16 + quad*8) : z;
    }
    // V A-frags: A[row=d=l16][k=m]; planar V: row rr, 8 consecutive cols
    short8 va0, va1;
    {
        const short* vb = Vp + ((size_t)(b*64 + h*16 + l16))*NPX;
        const short* p0 = vb + (row0 + quad)*NHW + col0;
        const short* p1 = vb + (row0 + 4 + quad)*NHW + col0;
        short4v a = *(const short4v*)p0, bq = *(const short4v*)(p0 + 4);
        short4v c = *(const short4v*)p1, d = *(const short4v*)(p1 + 4);
        #pragma unroll
        for (int j = 0; j < 4; ++j) { va0[j] = a[j]; va0[4+j] = bq[j]; va1[j] = c[j]; va1[4+j] = d[j]; }
    }

    #pragma unroll
    for (int ntl = 0; ntl < 4; ++ntl) {
        int n = ntl*16 + l16;
        int px = (row0 + (n >> 3))*NHW + col0 + (n & 7);
        short8 qa = (quad < 2) ? *(const short8*)(Qp + ((size_t)b*NPX + px)*64 + h*16 + quad*8) : z;
        f4 s[4];
        #pragma unroll
        for (int mt = 0; mt < 4; ++mt) {
            f4 acc = {0.f,0.f,0.f,0.f};
            s[mt] = MFMA(qa, kb[mt], acc);
        }
        // softmax over m (4 regs x 16 lanes); no max pass (|S|*0.25 << 30), clamp for safety
        f4 sum = {0.f,0.f,0.f,0.f};
        #pragma unroll
        for (int mt = 0; mt < 4; ++mt)
            #pragma unroll
            for (int r = 0; r < 4; ++r) {
                float e = __expf(fminf(s[mt][r]*0.25f, 30.f));
                s[mt][r] = e; sum[r] += e;
            }
        #pragma unroll
        for (int d = 1; d < 16; d <<= 1)
            #pragma unroll
            for (int r = 0; r < 4; ++r) sum[r] += __shfl_xor(sum[r], d);
        #pragma unroll
        for (int r = 0; r < 4; ++r) sum[r] = 1.f / sum[r];
        #pragma unroll
        for (int mt = 0; mt < 4; ++mt)
            #pragma unroll
            for (int r = 0; r < 4; ++r)
                PT[SWV(quad*4 + r, mt*16 + l16)] = f2bf(s[mt][r] * sum[r]);
        // O[d][n] = V_h P^T  (in-wave LDS RAW, waitcnt-ordered; no barrier needed)
        f4 o = {0.f,0.f,0.f,0.f};
        o = MFMA(va0, *(const short8*)(PT + SWV(l16, quad*8)), o);
        o = MFMA(va1, *(const short8*)(PT + SWV(l16, 32 + quad*8)), o);
        short4v sv;
        #pragma unroll
        for (int r = 0; r < 4; ++r) sv[r] = f2bf(o[r]);
        *(short4v*)(scrp + (((size_t)(parity*nb + b))*NPX + px)*64 + h*16 + quad*4) = sv;
    }
}

// ---------------- fold from parity planes + mask + 1x1 proj + residual ----------------
__global__ __launch_bounds__(256, 6) void k_gather(
    const short* __restrict__ scr, size_t scr_stride,
    const float* __restrict__ r0, const float* __restrict__ r1,
    const float* __restrict__ wp0, const float* __restrict__ wp1,
    float* __restrict__ o0, float* __restrict__ o1, int nb) {
    __shared__ __align__(16) short G[8192];       // [px 0..127][64 ch], swizzled
    int bidx = blockIdx.x;
    int per = nb * NHW;
    int pass = bidx / per; int rem2 = bidx - pass*per;
    int b = rem2 >> 7, hh = rem2 & 127;
    const short* scrp = scr + (size_t)pass * scr_stride;
    const float* resid = pass ? r1 : r0;
    const float* wproj = pass ? wp1 : wp0;
    float* outp = pass ? o1 : o0;
    int t = threadIdx.x;
    int p = t >> 1, c0 = (t & 1)*32;
    int rlo, rhi, clo, chi;
    wrange(hh, rlo, rhi); wrange(p, clo, chi);
    float vr[2], vc[2];
    vr[0] = (rhi > rlo || (rlo & 1) == 0) ? 1.f : 0.f;
    vr[1] = (rhi > rlo || (rlo & 1) == 1) ? 1.f : 0.f;
    vc[0] = (chi > clo || (clo & 1) == 0) ? 1.f : 0.f;
    vc[1] = (chi > clo || (clo & 1) == 1) ? 1.f : 0.f;
    float g[32];
    #pragma unroll
    for (int k = 0; k < 32; ++k) g[k] = 0.f;
    #pragma unroll
    for (int par = 0; par < 4; ++par) {
        float wgt = vr[par >> 1] * vc[par & 1];
        const short* srcp = scrp + (((size_t)(par*nb + b))*NPX + hh*NHW + p)*64 + c0;
        #pragma unroll
        for (int k4 = 0; k4 < 4; ++k4) {
            short8 v = *(const short8*)(srcp + k4*8);
            #pragma unroll
            for (int j = 0; j < 8; ++j) g[k4*8 + j] += wgt * bf2f(v[j]);
        }
    }
    float inv = 1.f / ((float)(rhi - rlo + 1) * (float)(chi - clo + 1));
    #pragma unroll
    for (int k4 = 0; k4 < 4; ++k4) {
        short8 v;
        #pragma unroll
        for (int j = 0; j < 8; ++j) v[j] = f2bf(g[k4*8 + j] * inv);
        *(short8*)(G + SWV(p, c0 + k4*8)) = v;
    }
    __syncthreads();
    int w = t >> 6, ln = t & 63, l16 = ln & 15, quad = ln >> 4;
    short8 wa0, wa1;
    {
        const float* p0 = wproj + (16*w + l16)*64 + quad*8;
        #pragma unroll
        for (int j = 0; j < 8; ++j) { wa0[j] = f2bf(p0[j]); wa1[j] = f2bf(p0[32 + j]); }
    }
    #pragma unroll
    for (int pt = 0; pt < 8; ++pt) {
        f4 acc = {0.f,0.f,0.f,0.f};
        acc = MFMA(wa0, *(const short8*)(G + SWV(pt*16 + l16, quad*8)), acc);
        acc = MFMA(wa1, *(const short8*)(G + SWV(pt*16 + l16, 32 + quad*8)), acc);
        #pragma unroll
        for (int r = 0; r < 4; ++r) {
            size_t gi = (((size_t)(b*64 + 16*w + quad*4 + r))*NHW + hh)*NHW + pt*16 + l16;
            outp[gi] = resid[gi] + acc[r];
        }
    }
}

extern "C" void kernel_launch(void* const* d_in, const int* in_sizes, int n_in,
                              void* d_out, int out_size, void* d_ws, size_t ws_size,
                              hipStream_t stream) {
    const float* low  = (const float*)d_in[0];
    const float* high = (const float*)d_in[1];
    const float* w_ql = (const float*)d_in[2];
    const float* w_kh = (const float*)d_in[3];
    const float* w_vh = (const float*)d_in[4];
    const float* w_qh = (const float*)d_in[5];
    const float* w_kl = (const float*)d_in[6];
    const float* w_vl = (const float*)d_in[7];
    const float* w_pl = (const float*)d_in[8];
    const float* w_ph = (const float*)d_in[9];
    float* out = (float*)d_out;
    float* pooled = (float*)d_ws;
    float* sgate  = pooled + 256;
    short* base = (short*)((char*)d_ws + 2048);
    const size_t PL = (size_t)NB * NPX * 64;            // elems per bf16 plane (8.39 MB)
    const size_t plane_f = (size_t)NB * 64 * NPX;       // fp32 out plane elems
    const size_t SCR = 4 * PL;                          // scr elems per pass (33.5 MB)
    size_t need_fused  = 2048 + (6*PL + 2*SCR) * sizeof(short);
    size_t need_serial = 2048 + (6*PL + SCR) * sizeof(short);
    size_t scr_elems_per_b = 4 * (size_t)NPX * 64;

    k_pool<<<dim3(NB*64), dim3(256), 0, stream>>>(high, pooled);
    k_gate<<<dim3(1), dim3(256), 0, stream>>>(pooled,
        (const float*)d_in[10], (const float*)d_in[11],
        (const float*)d_in[12], (const float*)d_in[13],
        (const float*)d_in[14], (const float*)d_in[15], sgate);

    if (ws_size >= need_serial) {
        short* QL = base;        short* KL = base + PL;   short* VL = base + 2*PL;
        short* QH = base + 3*PL; short* KH = base + 4*PL; short* VH = base + 5*PL;
        short* scr = base + 6*PL;
        k_proj<7><<<dim3(NB*NHW), dim3(256), 0, stream>>>(low,  nullptr, w_ql, w_kl, w_vl, QL, KL, VL);
        k_proj<7><<<dim3(NB*NHW), dim3(256), 0, stream>>>(high, sgate,   w_qh, w_kh, w_vh, QH, KH, VH);
        if (ws_size >= need_fused) {
            // both passes, XCD-swizzled: blockIdx%8 = (pass,b) region
            k_attn<1><<<dim3(8*NL), dim3(256), 0, stream>>>(QL, KH, VH, QH, KL, VL, scr, SCR, NB);
            k_gather<<<dim3(2*NB*NHW), dim3(256), 0, stream>>>(scr, SCR, low, high,
                w_pl, w_ph, out, out + plane_f, NB);
        } else {
            k_attn<0><<<dim3(NB*NL), dim3(256), 0, stream>>>(QL, KH, VH, nullptr, nullptr, nullptr, scr, 0, NB);
            k_gather<<<dim3(NB*NHW), dim3(256), 0, stream>>>(scr, 0, low, nullptr,
                w_pl, nullptr, out, nullptr, NB);
            k_attn<0><<<dim3(NB*NL), dim3(256), 0, stream>>>(QH, KL, VL, nullptr, nullptr, nullptr, scr, 0, NB);
            k_gather<<<dim3(NB*NHW), dim3(256), 0, stream>>>(scr, 0, high, nullptr,
                w_ph, nullptr, out + plane_f, nullptr, NB);
        }
    } else {
        // trio mode: 3 plane slots + batch-chunked scr
        short* P0 = base; short* P1 = base + PL; short* P2 = base + 2*PL;
        short* scr = base + 3*PL;
        int nbc = 0;
        for (int n = NB; n >= 1; n >>= 1)
            if (ws_size >= 2048 + (3*PL + n*scr_elems_per_b)*sizeof(short)) { nbc = n; break; }
        if (nbc == 0) nbc = 1;
        for (int pass = 0; pass < 2; ++pass) {
            const float* qsrc = pass ? high : low;
            const float* ksrc = pass ? low  : high;
            const float* qg   = pass ? sgate : nullptr;
            const float* kg   = pass ? nullptr : sgate;
            const float* Wq   = pass ? w_qh : w_ql;
            const float* Wk   = pass ? w_kl : w_kh;
            const float* Wv   = pass ? w_vl : w_vh;
            const float* Wp   = pass ? w_ph : w_pl;
            const float* resid = pass ? high : low;
            float* op = out + (size_t)pass * plane_f;
            k_proj<1><<<dim3(NB*NHW), dim3(256), 0, stream>>>(qsrc, qg, Wq, nullptr, nullptr, P0, nullptr, nullptr);
            k_proj<6><<<dim3(NB*NHW), dim3(256), 0, stream>>>(ksrc, kg, nullptr, Wk, Wv, nullptr, P1, P2);
            for (int b0 = 0; b0 < NB; b0 += nbc) {
                int nb = (NB - b0) < nbc ? (NB - b0) : nbc;
                size_t boff = (size_t)b0 * NPX * 64;
                k_attn<0><<<dim3(nb*NL), dim3(256), 0, stream>>>(P0 + boff, P1 + boff, P2 + boff,
                    nullptr, nullptr, nullptr, scr, 0, nb);
                k_gather<<<dim3(nb*NHW), dim3(256), 0, stream>>>(scr, 0, resid + boff, nullptr,
                    Wp, nullptr, op + boff, nullptr, nb);
            }
        }
    }
}

// Round 8
// 218.294 us; speedup vs baseline: 1.4555x; 1.1298x over previous
//
#include <hip/hip_runtime.h>

typedef short short8 __attribute__((ext_vector_type(8)));
typedef short short4v __attribute__((ext_vector_type(4)));
typedef float f4 __attribute__((ext_vector_type(4)));

#define NB 4
#define NHW 128
#define NPX (NHW*NHW)
#define NWIN 31
#define NL (NWIN*NWIN)
// 64-wide row, 8-col-block XOR swizzle (conflict-free b128 row reads)
#define SWV(r,c) (((r)<<6) + (((((c)>>3) ^ ((r)&7))<<3) | ((c)&7)))
#define MFMA(a,b,c) __builtin_amdgcn_mfma_f32_16x16x32_bf16(a,b,c,0,0,0)

__device__ __forceinline__ short f2bf(float f) {
    unsigned u = __float_as_uint(f);
    u += 0x7fffu + ((u >> 16) & 1u);   // RNE; inputs never NaN/inf
    return (short)(u >> 16);
}
__device__ __forceinline__ short f2bft(float f) {   // truncate (P only; self-normalized)
    return (short)(__float_as_uint(f) >> 16);
}
__device__ __forceinline__ float bf2f(short v) {
    return __uint_as_float(((unsigned)(unsigned short)v) << 16);
}

// ---------------- SE: global average pool per (b,c) ----------------
__global__ void k_pool(const float* __restrict__ high, float* __restrict__ pooled) {
    int bc = blockIdx.x;
    const float* src = high + (size_t)bc * NPX;
    float s = 0.f;
    for (int i = threadIdx.x; i < NPX; i += 256) s += src[i];
    for (int off = 32; off > 0; off >>= 1) s += __shfl_down(s, off);
    __shared__ float red[4];
    int lane = threadIdx.x & 63, wv = threadIdx.x >> 6;
    if (lane == 0) red[wv] = s;
    __syncthreads();
    if (threadIdx.x == 0)
        pooled[bc] = (red[0] + red[1] + red[2] + red[3]) * (1.f / NPX);
}

// ---------------- SE: gate s[b,c] ----------------
__global__ void k_gate(const float* __restrict__ pooled,
                       const float* __restrict__ w10, const float* __restrict__ w20,
                       const float* __restrict__ w11, const float* __restrict__ w21,
                       const float* __restrict__ w12, const float* __restrict__ w22,
                       float* __restrict__ sgate) {
    __shared__ float pl[256];
    int t = threadIdx.x;
    pl[t] = pooled[t];
    __syncthreads();
    int b = t >> 6, c = t & 63;
    const float* w1; const float* w2; int o0, gc;
    if (c < 22)      { w1 = w10; w2 = w20; o0 = 0;  gc = 22; }
    else if (c < 43) { w1 = w11; w2 = w21; o0 = 22; gc = 21; }
    else             { w1 = w12; w2 = w22; o0 = 43; gc = 21; }
    float a = 0.f;
    for (int k = 0; k < gc; ++k) a += pl[b*64 + o0 + k] * w1[k];
    a = fmaxf(a, 0.f);
    float z = a * w2[c - o0];
    sgate[t] = 1.f / (1.f + __expf(-z));
}

// windows covering coordinate x (ws=8, stride 4): [lo,hi]
__device__ __forceinline__ void wrange(int x, int& lo, int& hi) {
    lo = (x >= 7) ? ((x - 4) >> 2) : 0;
    hi = x >> 2; if (hi > 30) hi = 30;
}

// ---------------- projection body (shared) ----------------
// Q is pre-scaled by 0.25 (attention scale folded in).
template<int EMIT>
__device__ __forceinline__ void proj_body(
    const float* __restrict__ src, const float* __restrict__ gate,
    const float* __restrict__ Wq, const float* __restrict__ Wk, const float* __restrict__ Wv,
    short* __restrict__ Qp, short* __restrict__ Kp, short* __restrict__ Vp,
    short* T, int b, int row, int t) {
    const float* sp = src + (size_t)b*64*NPX + row*NHW;
    #pragma unroll
    for (int i = 0; i < 8; ++i) {
        int f = t + i*256;
        int c = f & 63, px = (f >> 6) << 2;
        float4 v = *(const float4*)(sp + (size_t)c*NPX + px);
        float g = gate ? gate[b*64 + c] : 1.f;
        T[SWV(px + 0, c)] = f2bf(v.x * g);
        T[SWV(px + 1, c)] = f2bf(v.y * g);
        T[SWV(px + 2, c)] = f2bf(v.z * g);
        T[SWV(px + 3, c)] = f2bf(v.w * g);
    }
    __syncthreads();
    int w = t >> 6, ln = t & 63, l16 = ln & 15, quad = ln >> 4;
    int orow = 16*w + l16;
    short8 wq[2], wk[2], wv[2];
    #pragma unroll
    for (int kf = 0; kf < 2; ++kf) {
        if (EMIT & 1) {
            const float* p = Wq + orow*64 + kf*32 + quad*8;
            #pragma unroll
            for (int j = 0; j < 8; ++j) wq[kf][j] = f2bf(p[j]);
        }
        if (EMIT & 2) {
            const float* p = Wk + orow*64 + kf*32 + quad*8;
            #pragma unroll
            for (int j = 0; j < 8; ++j) wk[kf][j] = f2bf(p[j]);
        }
        if (EMIT & 4) {
            const float* p = Wv + orow*64 + kf*32 + quad*8;
            #pragma unroll
            for (int j = 0; j < 8; ++j) wv[kf][j] = f2bf(p[j]);
        }
    }
    #pragma unroll
    for (int nt = 0; nt < 8; ++nt) {
        int px = nt*16 + l16;
        short8 xb0 = *(const short8*)(T + SWV(px, quad*8));
        short8 xb1 = *(const short8*)(T + SWV(px, 32 + quad*8));
        size_t clbase = ((size_t)b*NPX + row*NHW + px)*64 + 16*w + quad*4;
        if (EMIT & 1) {
            f4 acc = {0.f,0.f,0.f,0.f};
            acc = MFMA(wq[0], xb0, acc); acc = MFMA(wq[1], xb1, acc);
            short4v sv;
            #pragma unroll
            for (int r = 0; r < 4; ++r) sv[r] = f2bf(acc[r] * 0.25f);
            *(short4v*)(Qp + clbase) = sv;
        }
        if (EMIT & 2) {
            f4 acc = {0.f,0.f,0.f,0.f};
            acc = MFMA(wk[0], xb0, acc); acc = MFMA(wk[1], xb1, acc);
            short4v sv;
            #pragma unroll
            for (int r = 0; r < 4; ++r) sv[r] = f2bf(acc[r]);
            *(short4v*)(Kp + clbase) = sv;
        }
        if (EMIT & 4) {
            f4 acc = {0.f,0.f,0.f,0.f};
            acc = MFMA(wv[0], xb0, acc); acc = MFMA(wv[1], xb1, acc);
            #pragma unroll
            for (int r = 0; r < 4; ++r)
                Vp[((size_t)(b*64 + 16*w + quad*4 + r))*NPX + row*NHW + px] = f2bf(acc[r]);
        }
    }
}

// single-source projection (fallback paths)
template<int EMIT>
__global__ __launch_bounds__(256, 6) void k_proj(
    const float* __restrict__ src, const float* __restrict__ gate,
    const float* __restrict__ Wq, const float* __restrict__ Wk, const float* __restrict__ Wv,
    short* __restrict__ Qp, short* __restrict__ Kp, short* __restrict__ Vp) {
    __shared__ __align__(16) short T[8192];
    proj_body<EMIT>(src, gate, Wq, Wk, Wv, Qp, Kp, Vp, T,
                    blockIdx.x >> 7, blockIdx.x & 127, threadIdx.x);
}

// fused both-source projection: bidx&7 = (srcsel<<2)|b region -> XCD-local
__global__ __launch_bounds__(256, 6) void k_proj2(
    const float* __restrict__ s0, const float* __restrict__ s1, const float* __restrict__ gate,
    const float* __restrict__ Wq0, const float* __restrict__ Wk0, const float* __restrict__ Wv0,
    const float* __restrict__ Wq1, const float* __restrict__ Wk1, const float* __restrict__ Wv1,
    short* __restrict__ Q0, short* __restrict__ K0, short* __restrict__ V0,
    short* __restrict__ Q1, short* __restrict__ K1, short* __restrict__ V1) {
    __shared__ __align__(16) short T[8192];
    int region = blockIdx.x & 7;
    int ss = region >> 2, b = region & 3, row = blockIdx.x >> 3;
    if (ss == 0)
        proj_body<7>(s0, nullptr, Wq0, Wk0, Wv0, Q0, K0, V0, T, b, row, threadIdx.x);
    else
        proj_body<7>(s1, gate, Wq1, Wk1, Wv1, Q1, K1, V1, T, b, row, threadIdx.x);
}

// ---------------- windowed cross attention (S, softmax, PV only) ----------------
// SWZ=1 (fused, grid=8*NL): blockIdx%8 -> (pass,b): each XCD owns one plane.
// Softmax denominator via MFMA ones-trick: O = (V*P_hat) * rcp(sum(P_hat)),
// P_hat stored unnormalized (truncating bf16; normalization self-consistent).
// scr: [pass][4 parity][nb][px][64] bf16; same-parity windows tile the plane.
template<int SWZ>
__global__ __launch_bounds__(256, 6) void k_attn(
    const short* __restrict__ Q0, const short* __restrict__ K0, const short* __restrict__ V0,
    const short* __restrict__ Q1, const short* __restrict__ K1, const short* __restrict__ V1,
    short* __restrict__ scr, size_t scr_stride, int nb) {
    __shared__ __align__(16) short Pb[4][1024];   // per-wave P [16 n][64 m], swizzled
    int bidx = blockIdx.x;
    int pass, b, l;
    if (SWZ) {
        int region = bidx & 7;
        pass = region >> 2; b = region & 3; l = bidx >> 3;
    } else {
        int per = nb * NL;
        pass = bidx / per; int rem2 = bidx - pass*per;
        b = rem2 / NL; l = rem2 - b*NL;
    }
    const short* Qp = pass ? Q1 : Q0;
    const short* Kp = pass ? K1 : K0;
    const short* Vp = pass ? V1 : V0;
    short* scrp = scr + (size_t)pass * scr_stride;
    int wr = l / NWIN, wc = l - (l/NWIN)*NWIN;
    int row0 = wr*4, col0 = wc*4;
    int parity = (wr & 1)*2 + (wc & 1);
    int t = threadIdx.x, w = t >> 6, ln = t & 63, l16 = ln & 15, quad = ln >> 4;
    int h = w;
    short* PT = Pb[w];
    short8 z = {0,0,0,0,0,0,0,0};
    const short one = (short)0x3F80;   // bf16 1.0
    short8 ones = {one,one,one,one,one,one,one,one};

    // K B-frags: B[k=d][col=m], m = mt*16+l16, d = quad*8+j (quad<2)
    short8 kb[4];
    #pragma unroll
    for (int mt = 0; mt < 4; ++mt) {
        int m = mt*16 + l16;
        int px = (row0 + (m >> 3))*NHW + col0 + (m & 7);
        kb[mt] = (quad < 2) ? *(const short8*)(Kp + ((size_t)b*NPX + px)*64 + h*16 + quad*8) : z;
    }
    // V A-frags: A[row=d=l16][k=m]; planar V: row rr, 8 consecutive cols
    short8 va0, va1;
    {
        const short* vb = Vp + ((size_t)(b*64 + h*16 + l16))*NPX;
        const short* p0 = vb + (row0 + quad)*NHW + col0;
        const short* p1 = vb + (row0 + 4 + quad)*NHW + col0;
        short4v a = *(const short4v*)p0, bq = *(const short4v*)(p0 + 4);
        short4v c = *(const short4v*)p1, d = *(const short4v*)(p1 + 4);
        #pragma unroll
        for (int j = 0; j < 4; ++j) { va0[j] = a[j]; va0[4+j] = bq[j]; va1[j] = c[j]; va1[4+j] = d[j]; }
    }

    #pragma unroll
    for (int ntl = 0; ntl < 4; ++ntl) {
        int n = ntl*16 + l16;
        int px = (row0 + (n >> 3))*NHW + col0 + (n & 7);
        short8 qa = (quad < 2) ? *(const short8*)(Qp + ((size_t)b*NPX + px)*64 + h*16 + quad*8) : z;
        f4 s[4];
        #pragma unroll
        for (int mt = 0; mt < 4; ++mt) {
            f4 acc = {0.f,0.f,0.f,0.f};
            s[mt] = MFMA(qa, kb[mt], acc);
        }
        // unnormalized exp (Q pre-scaled by 0.25; clamp for safety)
        #pragma unroll
        for (int mt = 0; mt < 4; ++mt)
            #pragma unroll
            for (int r = 0; r < 4; ++r)
                PT[SWV(quad*4 + r, mt*16 + l16)] = f2bft(__expf(fminf(s[mt][r], 30.f)));
        // O[d][n] = V_h P^T; denom[n] = ones * P^T (same B-frags, col-aligned)
        short8 pb0 = *(const short8*)(PT + SWV(l16, quad*8));
        short8 pb1 = *(const short8*)(PT + SWV(l16, 32 + quad*8));
        f4 o = {0.f,0.f,0.f,0.f};
        o = MFMA(va0, pb0, o);
        o = MFMA(va1, pb1, o);
        f4 dn = {0.f,0.f,0.f,0.f};
        dn = MFMA(ones, pb0, dn);
        dn = MFMA(ones, pb1, dn);
        float inv = __builtin_amdgcn_rcpf(dn[0]);
        short4v sv;
        #pragma unroll
        for (int r = 0; r < 4; ++r) sv[r] = f2bf(o[r] * inv);
        *(short4v*)(scrp + (((size_t)(parity*nb + b))*NPX + px)*64 + h*16 + quad*4) = sv;
    }
}

// ---------------- fold from parity planes + mask + 1x1 proj + residual ----------------
// Half-row blocks (64 px) for occupancy; SWZ=1: bidx&7 = (pass,b) region.
template<int SWZ>
__global__ __launch_bounds__(256, 6) void k_gather(
    const short* __restrict__ scr, size_t scr_stride,
    const float* __restrict__ r0, const float* __restrict__ r1,
    const float* __restrict__ wp0, const float* __restrict__ wp1,
    float* __restrict__ o0, float* __restrict__ o1, int nb) {
    __shared__ __align__(16) short G[4096];       // [64 px][64 ch], swizzled
    int bidx = blockIdx.x;
    int pass, b, hh, half;
    if (SWZ) {
        int region = bidx & 7;
        pass = region >> 2; b = region & 3;
        int rem2 = bidx >> 3; hh = rem2 >> 1; half = rem2 & 1;
    } else {
        pass = 0;
        b = bidx / (NHW*2); int rem2 = bidx - b*(NHW*2);
        hh = rem2 >> 1; half = rem2 & 1;
    }
    const short* scrp = scr + (size_t)pass * scr_stride;
    const float* resid = pass ? r1 : r0;
    const float* wproj = pass ? wp1 : wp0;
    float* outp = pass ? o1 : o0;
    int t = threadIdx.x;
    int ploc = t >> 2, c0 = (t & 3)*16;
    int p = half*64 + ploc;
    int rlo, rhi, clo, chi;
    wrange(hh, rlo, rhi); wrange(p, clo, chi);
    float vr[2], vc[2];
    vr[0] = (rhi > rlo || (rlo & 1) == 0) ? 1.f : 0.f;
    vr[1] = (rhi > rlo || (rlo & 1) == 1) ? 1.f : 0.f;
    vc[0] = (chi > clo || (clo & 1) == 0) ? 1.f : 0.f;
    vc[1] = (chi > clo || (clo & 1) == 1) ? 1.f : 0.f;
    float g[16];
    #pragma unroll
    for (int k = 0; k < 16; ++k) g[k] = 0.f;
    #pragma unroll
    for (int par = 0; par < 4; ++par) {
        float wgt = vr[par >> 1] * vc[par & 1];
        const short* srcp = scrp + (((size_t)(par*nb + b))*NPX + hh*NHW + p)*64 + c0;
        #pragma unroll
        for (int k8 = 0; k8 < 2; ++k8) {
            short8 v = *(const short8*)(srcp + k8*8);
            #pragma unroll
            for (int j = 0; j < 8; ++j) g[k8*8 + j] += wgt * bf2f(v[j]);
        }
    }
    float inv = 1.f / ((float)(rhi - rlo + 1) * (float)(chi - clo + 1));
    #pragma unroll
    for (int k8 = 0; k8 < 2; ++k8) {
        short8 v;
        #pragma unroll
        for (int j = 0; j < 8; ++j) v[j] = f2bf(g[k8*8 + j] * inv);
        *(short8*)(G + SWV(ploc, c0 + k8*8)) = v;
    }
    __syncthreads();
    int w = t >> 6, ln = t & 63, l16 = ln & 15, quad = ln >> 4;
    short8 wa0, wa1;
    {
        const float* p0 = wproj + (16*w + l16)*64 + quad*8;
        #pragma unroll
        for (int j = 0; j < 8; ++j) { wa0[j] = f2bf(p0[j]); wa1[j] = f2bf(p0[32 + j]); }
    }
    #pragma unroll
    for (int pt = 0; pt < 4; ++pt) {
        f4 acc = {0.f,0.f,0.f,0.f};
        acc = MFMA(wa0, *(const short8*)(G + SWV(pt*16 + l16, quad*8)), acc);
        acc = MFMA(wa1, *(const short8*)(G + SWV(pt*16 + l16, 32 + quad*8)), acc);
        #pragma unroll
        for (int r = 0; r < 4; ++r) {
            size_t gi = (((size_t)(b*64 + 16*w + quad*4 + r))*NHW + hh)*NHW + half*64 + pt*16 + l16;
            outp[gi] = resid[gi] + acc[r];
        }
    }
}

extern "C" void kernel_launch(void* const* d_in, const int* in_sizes, int n_in,
                              void* d_out, int out_size, void* d_ws, size_t ws_size,
                              hipStream_t stream) {
    const float* low  = (const float*)d_in[0];
    const float* high = (const float*)d_in[1];
    const float* w_ql = (const float*)d_in[2];
    const float* w_kh = (const float*)d_in[3];
    const float* w_vh = (const float*)d_in[4];
    const float* w_qh = (const float*)d_in[5];
    const float* w_kl = (const float*)d_in[6];
    const float* w_vl = (const float*)d_in[7];
    const float* w_pl = (const float*)d_in[8];
    const float* w_ph = (const float*)d_in[9];
    float* out = (float*)d_out;
    float* pooled = (float*)d_ws;
    float* sgate  = pooled + 256;
    short* base = (short*)((char*)d_ws + 2048);
    const size_t PL = (size_t)NB * NPX * 64;            // elems per bf16 plane (8.39 MB)
    const size_t plane_f = (size_t)NB * 64 * NPX;       // fp32 out plane elems
    const size_t SCR = 4 * PL;                          // scr elems per pass (33.5 MB)
    size_t need_fused  = 2048 + (6*PL + 2*SCR) * sizeof(short);
    size_t need_serial = 2048 + (6*PL + SCR) * sizeof(short);
    size_t scr_elems_per_b = 4 * (size_t)NPX * 64;

    k_pool<<<dim3(NB*64), dim3(256), 0, stream>>>(high, pooled);
    k_gate<<<dim3(1), dim3(256), 0, stream>>>(pooled,
        (const float*)d_in[10], (const float*)d_in[11],
        (const float*)d_in[12], (const float*)d_in[13],
        (const float*)d_in[14], (const float*)d_in[15], sgate);

    if (ws_size >= need_serial) {
        short* QL = base;        short* KL = base + PL;   short* VL = base + 2*PL;
        short* QH = base + 3*PL; short* KH = base + 4*PL; short* VH = base + 5*PL;
        short* scr = base + 6*PL;
        k_proj2<<<dim3(8*NHW), dim3(256), 0, stream>>>(low, high, sgate,
            w_ql, w_kl, w_vl, w_qh, w_kh, w_vh,
            QL, KL, VL, QH, KH, VH);
        if (ws_size >= need_fused) {
            k_attn<1><<<dim3(8*NL), dim3(256), 0, stream>>>(QL, KH, VH, QH, KL, VL, scr, SCR, NB);
            k_gather<1><<<dim3(8*NHW*2), dim3(256), 0, stream>>>(scr, SCR, low, high,
                w_pl, w_ph, out, out + plane_f, NB);
        } else {
            k_attn<0><<<dim3(NB*NL), dim3(256), 0, stream>>>(QL, KH, VH, nullptr, nullptr, nullptr, scr, 0, NB);
            k_gather<0><<<dim3(NB*NHW*2), dim3(256), 0, stream>>>(scr, 0, low, nullptr,
                w_pl, nullptr, out, nullptr, NB);
            k_attn<0><<<dim3(NB*NL), dim3(256), 0, stream>>>(QH, KL, VL, nullptr, nullptr, nullptr, scr, 0, NB);
            k_gather<0><<<dim3(NB*NHW*2), dim3(256), 0, stream>>>(scr, 0, high, nullptr,
                w_ph, nullptr, out + plane_f, nullptr, NB);
        }
    } else {
        // trio mode: 3 plane slots + batch-chunked scr
        short* P0 = base; short* P1 = base + PL; short* P2 = base + 2*PL;
        short* scr = base + 3*PL;
        int nbc = 0;
        for (int n = NB; n >= 1; n >>= 1)
            if (ws_size >= 2048 + (3*PL + n*scr_elems_per_b)*sizeof(short)) { nbc = n; break; }
        if (nbc == 0) nbc = 1;
        for (int pass = 0; pass < 2; ++pass) {
            const float* qsrc = pass ? high : low;
            const float* ksrc = pass ? low  : high;
            const float* qg   = pass ? sgate : nullptr;
            const float* kg   = pass ? nullptr : sgate;
            const float* Wq   = pass ? w_qh : w_ql;
            const float* Wk   = pass ? w_kl : w_kh;
            const float* Wv   = pass ? w_vl : w_vh;
            const float* Wp   = pass ? w_ph : w_pl;
            const float* resid = pass ? high : low;
            float* op = out + (size_t)pass * plane_f;
            k_proj<1><<<dim3(NB*NHW), dim3(256), 0, stream>>>(qsrc, qg, Wq, nullptr, nullptr, P0, nullptr, nullptr);
            k_proj<6><<<dim3(NB*NHW), dim3(256), 0, stream>>>(ksrc, kg, nullptr, Wk, Wv, nullptr, P1, P2);
            for (int b0 = 0; b0 < NB; b0 += nbc) {
                int nb = (NB - b0) < nbc ? (NB - b0) : nbc;
                size_t boff = (size_t)b0 * NPX * 64;
                k_attn<0><<<dim3(nb*NL), dim3(256), 0, stream>>>(P0 + boff, P1 + boff, P2 + boff,
                    nullptr, nullptr, nullptr, scr, 0, nb);
                k_gather<0><<<dim3(nb*NHW*2), dim3(256), 0, stream>>>(scr, 0, resid + boff, nullptr,
                    Wp, nullptr, op + boff, nullptr, nb);
            }
        }
    }
}